// Round 7
// baseline (1456.302 us; speedup 1.0000x reference)
//
#include <hip/hip_runtime.h>
#include <float.h>
#include <math.h>

#define B_   16
#define NB_  8192
#define M_   1024
#define K_   16

// ===================== FROZEN ARITHMETIC (verified absmax==0, rounds 5-8) ==
// FPS d2:  dx=px-lx... d2=(dx*dx+dy*dy)+dz*dz   f32, no FMA (contract off)
//          (packed v_pk_* f32 ops are per-half IEEE-identical to scalar)
// kNN:     pn2/cn2 ascending no-FMA; dot=fma(cz,qz,fma(cy,qy,cx*qx));
//          d2=(cn2-2f*dot)+pn2
// Ties: strictly-first occurrence (lowest index) everywhere.
// R15: REVERT R14's pk inline asm (compiler already packed; asm broke
// scheduling, +130us — bank conflicts proved kNN identical). ONE new variable:
// FPS exchange piggybacks the winner's COORDS on the key ({key,xyz} per wave,
// coords extracted via readlane from a per-lane spts[t*PPT+jp] read that
// overlaps the ballot) — removes the post-barrier dependent spts[best] b128
// broadcast (~120cy) from the serial chain. Coord values are bit-identical
// moves of the same spts element; winner selection still by identical u64 key
// (wv,~gi) max — semantics unchanged. kNN + ticket merge: R14 verbatim.
// ===========================================================================

typedef float v2f __attribute__((ext_vector_type(2)));

#define FPS_T 256
#define PPT   32
#define NPAIR (PPT/2)
#define NWAVE (FPS_T/64)

#define KNN_T   256
#define CHUNK   1024
#define GRP     8
#define BCAP    16
#define BSTRIDE 17

#define FPS_BLOCKS B_
#define WGS_PER_B  15            // chunk splits 1+2+4+8
#define KNN_BLOCKS (B_ * WGS_PER_B)   // 240
#define MAXSP      8             // partial slots per centroid (chunks 1-3)

// stable sorted insert into ascending top-16 (ties keep earlier/lower index)
__device__ __forceinline__ void topk_insert(float d2, int pi, float val[16], int idx[16])
{
    int r = 0;
    #pragma unroll
    for (int j = 0; j < 16; ++j) r += (val[j] <= d2) ? 1 : 0;
    #pragma unroll
    for (int j = 15; j >= 1; --j) {
        bool sh = (j > r);
        val[j] = sh ? val[j-1] : val[j];
        idx[j] = sh ? idx[j-1] : idx[j];
    }
    #pragma unroll
    for (int j = 0; j < 16; ++j) {
        bool pl = (j == r);
        val[j] = pl ? d2 : val[j];
        idx[j] = pl ? pi : idx[j];
    }
}

// ============================= fused FPS + kNN =============================
__global__ __launch_bounds__(FPS_T, 1) void fused_kernel(
    const float* __restrict__ pos, float* __restrict__ cent,
    float* __restrict__ groups, unsigned long long* __restrict__ partials,
    unsigned int* __restrict__ progress)
{
    #pragma clang fp contract(off)
    __shared__ float4 spts[NB_];                        // FPS: 128 KB table; kNN carves prefix
    __shared__ unsigned long long wkey[2][NWAVE];       // FPS keys; kNN ticket scratch
    __shared__ float4 wxyz[2][NWAVE];                   // FPS winner coords (piggyback)

    const int blk = blockIdx.x;
    const int t   = threadIdx.x;

    if (blk < FPS_BLOCKS) {
        // ================= FPS role (R10-verified math; exchange surgery) =========
        const int b = blk;
        const float* pb = pos + (size_t)b * NB_ * 3;
        float* cb = cent + (size_t)b * M_ * 3;

        for (int p = t; p < NB_; p += FPS_T) {
            const float* s = pb + (size_t)p * 3;
            spts[p] = make_float4(s[0], s[1], s[2], 0.0f);
        }

        v2f px2[NPAIR], py2[NPAIR], pz2[NPAIR], md2[NPAIR];
        #pragma unroll
        for (int jj = 0; jj < NPAIR; ++jj) {
            const float* s0 = pb + (size_t)(t*PPT + 2*jj) * 3;
            px2[jj] = (v2f){s0[0], s0[3]};
            py2[jj] = (v2f){s0[1], s0[4]};
            pz2[jj] = (v2f){s0[2], s0[5]};
            md2[jj] = (v2f){FLT_MAX, FLT_MAX};
        }
        __syncthreads();

        float lx = pb[0], ly = pb[1], lz = pb[2];   // deterministic start at idx 0
        // thread t owns centroids 4t..4t+3 (named regs: no dynamic indexing)
        float c0x=0,c0y=0,c0z=0,c1x=0,c1y=0,c1z=0,c2x=0,c2y=0,c2z=0,c3x=0,c3y=0,c3z=0;

        for (int m = 0; m < M_; ++m) {
            if (t == (m >> 2)) {
                const int sl = m & 3;
                if      (sl == 0) { c0x=lx; c0y=ly; c0z=lz; }
                else if (sl == 1) { c1x=lx; c1y=ly; c1z=lz; }
                else if (sl == 2) { c2x=lx; c2y=ly; c2z=lz; }
                else              { c3x=lx; c3y=ly; c3z=lz; }
            }

            // ---- chunk flush: wave cg publishes centroids [256cg, 256cg+255] ----
            if ((m & 255) == 255) {
                const int cg = m >> 8;
                if ((t >> 6) == cg) {                       // thread t owns 4t..4t+3
                    float4* o = (float4*)(cb + (size_t)t * 12);
                    o[0] = make_float4(c0x, c0y, c0z, c1x);
                    o[1] = make_float4(c1y, c1z, c2x, c2y);
                    o[2] = make_float4(c2z, c3x, c3y, c3z);
                    if ((t & 63) == 0)                      // lane0 of wave cg: release
                        __hip_atomic_store(&progress[b], (unsigned)(cg + 1),
                                           __ATOMIC_RELEASE, __HIP_MEMORY_SCOPE_AGENT);
                }
            }
            if (m == M_ - 1) break;

            // ---- packed update + packed running max (frozen, r8-verified) ----
            const v2f lxv = {lx,lx}, lyv = {ly,ly}, lzv = {lz,lz};
            v2f bmax2 = {-1.0f, -1.0f};
            #pragma unroll
            for (int jj = 0; jj < NPAIR; ++jj) {
                v2f dx = px2[jj] - lxv;
                v2f dy = py2[jj] - lyv;
                v2f dz = pz2[jj] - lzv;
                v2f d2 = (dx*dx + dy*dy) + dz*dz;       // pk mul/add, frozen rounding
                v2f mj = __builtin_elementwise_min(md2[jj], d2);
                md2[jj] = mj;
                bmax2 = __builtin_elementwise_max(bmax2, mj);
            }
            float bm = fmaxf(bmax2.x, bmax2.y);

            // ---- wave f32 max via DPP (r7/r8-verified chain) ----
            float v = bm;
            {
                int vi;
                vi = __builtin_amdgcn_update_dpp(__float_as_int(v), __float_as_int(v), 0xB1,  0xF, 0xF, false);
                v = fmaxf(v, __int_as_float(vi));
                vi = __builtin_amdgcn_update_dpp(__float_as_int(v), __float_as_int(v), 0x4E,  0xF, 0xF, false);
                v = fmaxf(v, __int_as_float(vi));
                vi = __builtin_amdgcn_update_dpp(__float_as_int(v), __float_as_int(v), 0x141, 0xF, 0xF, false);
                v = fmaxf(v, __int_as_float(vi));
                vi = __builtin_amdgcn_update_dpp(__float_as_int(v), __float_as_int(v), 0x140, 0xF, 0xF, false);
                v = fmaxf(v, __int_as_float(vi));
                vi = __builtin_amdgcn_update_dpp(__float_as_int(v), __float_as_int(v), 0x142, 0xF, 0xF, false);
                v = fmaxf(v, __int_as_float(vi));
                vi = __builtin_amdgcn_update_dpp(__float_as_int(v), __float_as_int(v), 0x143, 0xF, 0xF, false);
                v = fmaxf(v, __int_as_float(vi));
            }
            const float wv = __int_as_float(__builtin_amdgcn_readlane(__float_as_int(v), 63));

            // ---- per-lane first-match scan (descending overwrite => lowest idx) ----
            int jp = -1;
            #pragma unroll
            for (int jj = NPAIR - 1; jj >= 0; --jj) {
                if (md2[jj].y == wv) jp = 2*jj + 1;
                if (md2[jj].x == wv) jp = 2*jj;
            }
            // candidate coords for my slot (clamped; only winner lane's value used)
            const int js = (jp >= 0) ? jp : 0;
            const float4 cc = spts[t*PPT + js];             // per-lane read, overlaps ballot
            const unsigned long long mk = __ballot(jp >= 0);
            const int wl = (int)__ffsll(mk) - 1;            // lowest lane == lowest block
            const int gi = __builtin_amdgcn_readlane(t*PPT + jp, wl);
            const float wx = __int_as_float(__builtin_amdgcn_readlane(__float_as_int(cc.x), wl));
            const float wy = __int_as_float(__builtin_amdgcn_readlane(__float_as_int(cc.y), wl));
            const float wz = __int_as_float(__builtin_amdgcn_readlane(__float_as_int(cc.z), wl));

            const int par = m & 1;
            if ((t & 63) == 0) {
                wkey[par][t >> 6] = ((unsigned long long)__float_as_uint(wv) << 32) |
                                    (unsigned int)(~gi);    // bigger ~idx == lower idx
                wxyz[par][t >> 6] = make_float4(wx, wy, wz, 0.0f);
            }
            __syncthreads();                                // the ONLY barrier

            // ---- select max-key slot; take its coords (no dependent spts read) ----
            unsigned long long kk = wkey[par][0];
            float bx = wxyz[par][0].x, by = wxyz[par][0].y, bz = wxyz[par][0].z;
            #pragma unroll
            for (int w = 1; w < NWAVE; ++w) {
                const unsigned long long e = wkey[par][w];
                const float4 exyz = wxyz[par][w];
                const bool gt = (e > kk);
                kk = gt ? e : kk;
                bx = gt ? exyz.x : bx;
                by = gt ? exyz.y : by;
                bz = gt ? exyz.z : bz;
            }
            lx = bx; ly = by; lz = bz;
        }
        return;
    }

    // ================= kNN role (R10-verified loop, verbatim) =================
    // per batch: 15 WGs -> chunk0 split1, chunk1 split2, chunk2 split4, chunk3 split8
    const int r = blk - FPS_BLOCKS;          // 0..239
    const int b = r / WGS_PER_B;
    const int w = r % WGS_PER_B;
    int cg, sp;
    if      (w == 0) { cg = 0; sp = 0; }
    else if (w < 3)  { cg = 1; sp = w - 1; }
    else if (w < 7)  { cg = 2; sp = w - 3; }
    else             { cg = 3; sp = w - 7; }
    const int span   = NB_ >> cg;
    const int pbase  = sp * span;
    const int direct = (cg == 0);
    const int nchunks = span / CHUNK;

    // carve kNN LDS out of the (unused-by-this-role) 128KB table
    float4* kpts = spts;                                              // 16 KB: x,y,z,pn2
    unsigned long long* sbuf = (unsigned long long*)(spts + CHUNK);   // ~34 KB

    const float* pb = pos + (size_t)b * NB_ * 3;

    // ---- pre-stage first chunk BEFORE the wait (centroid-independent) ----
    for (int p = t; p < CHUNK; p += KNN_T) {
        const float* s = pb + (size_t)(pbase + p) * 3;
        float x = s[0], y = s[1], z = s[2];
        float pn2 = (x*x + y*y) + z*z;               // ascending, no fma
        kpts[p] = make_float4(x, y, z, pn2);
    }

    // wait for producer: chunk cg's centroids are final once progress[b] > cg
    if (t == 0) {
        while (__hip_atomic_load(&progress[b], __ATOMIC_ACQUIRE,
                                 __HIP_MEMORY_SCOPE_AGENT) < (unsigned)(cg + 1))
            __builtin_amdgcn_s_sleep(64);
    }
    __syncthreads();                                  // wake + staging barrier

    const int mg = b * M_ + cg * KNN_T + t;
    const float cx = cent[(size_t)mg*3+0];
    const float cy = cent[(size_t)mg*3+1];
    const float cz = cent[(size_t)mg*3+2];
    const float cn2 = (cx*cx + cy*cy) + cz*cz;        // ascending, no fma

    float val[16]; int idx[16];
    #pragma unroll
    for (int j = 0; j < 16; ++j) { val[j] = FLT_MAX; idx[j] = 0; }
    float tau = FLT_MAX;
    int cnt = 0;
    unsigned long long* mybuf = sbuf + t * BSTRIDE;

    for (int c = 0; c < nchunks; ++c) {
        const int ps = pbase + c * CHUNK;

        for (int p0 = 0; p0 < CHUNK; p0 += GRP) {
            // make room BEFORE the group (appends per group <= GRP=8)
            if (__any(cnt > BCAP - GRP)) {
                int n = cnt; cnt = 0;
                for (int i = 0; i < n; ++i) {
                    unsigned long long e = mybuf[i];
                    float d = __uint_as_float((unsigned int)(e >> 32));
                    int pi  = (int)(e & 0xFFFFFFFFu);
                    if (d < val[15]) topk_insert(d, pi, val, idx);
                }
                tau = val[15];
            }
            float4 q[GRP];
            #pragma unroll
            for (int i = 0; i < GRP; ++i) q[i] = kpts[p0 + i];   // batched b128 reads
            float d2v[GRP];
            #pragma unroll
            for (int i = 0; i < GRP; ++i) {
                float dot = __builtin_fmaf(cz, q[i].z,
                            __builtin_fmaf(cy, q[i].y, cx * q[i].x)); // Eigen gemm k-rem
                d2v[i] = (cn2 - 2.0f*dot) + q[i].w;                   // no fma
            }
            #pragma unroll
            for (int i = 0; i < GRP; ++i) {
                if (d2v[i] < tau) {
                    mybuf[cnt] = ((unsigned long long)__float_as_uint(d2v[i]) << 32) |
                                 (unsigned int)(ps + p0 + i);
                    ++cnt;
                }
            }
        }

        if (c + 1 < nchunks) {                        // stage next chunk
            __syncthreads();
            const int ns = pbase + (c + 1) * CHUNK;
            for (int p = t; p < CHUNK; p += KNN_T) {
                const float* s = pb + (size_t)(ns + p) * 3;
                float x = s[0], y = s[1], z = s[2];
                float pn2 = (x*x + y*y) + z*z;        // ascending, no fma
                kpts[p] = make_float4(x, y, z, pn2);
            }
            __syncthreads();
        }
    }
    { // final flush
        int n = cnt;
        for (int i = 0; i < n; ++i) {
            unsigned long long e = mybuf[i];
            float d = __uint_as_float((unsigned int)(e >> 32));
            int pi  = (int)(e & 0xFFFFFFFFu);
            if (d < val[15]) topk_insert(d, pi, val, idx);
        }
    }

    if (direct) {
        float* g = groups + (size_t)mg * K_ * 3;
        #pragma unroll
        for (int kq = 0; kq < 16; ++kq) {
            const float* s = pb + (size_t)idx[kq] * 3;
            g[kq*3+0] = s[0]; g[kq*3+1] = s[1]; g[kq*3+2] = s[2];
        }
        return;
    }

    // ---- partial write + ticket: last split WG merges in-kernel (R12/R14-verified)
    const int cidx = b * 3 + (cg - 1);
    const int nsp  = 1 << cg;                         // 2 / 4 / 8
    {
        unsigned long long* o = partials + (((size_t)cidx * 256 + t) * MAXSP + sp) * 16;
        #pragma unroll
        for (int kq = 0; kq < 16; ++kq)
            o[kq] = ((unsigned long long)__float_as_uint(val[kq]) << 32) | (unsigned int)idx[kq];
    }
    __syncthreads();                                  // all waves' stores drained (vmcnt)
    unsigned int* counters = progress + 16;           // 48 u32, zeroed by host memset
    if (t == 0) {
        __threadfence();                              // writeback this XCD's L2 (release)
        wkey[0][0] = (unsigned long long)atomicAdd(&counters[cidx], 1u);
    }
    __syncthreads();
    if ((unsigned)wkey[0][0] != (unsigned)(nsp - 1))
        return;                                       // not last: done

    __threadfence();                                  // acquire other splits' partials
    {
        float mval[16]; int midx[16];
        #pragma unroll
        for (int j = 0; j < 16; ++j) { mval[j] = FLT_MAX; midx[j] = 0; }
        const unsigned long long* base2 = partials + (((size_t)cidx * 256 + t) * MAXSP) * 16;
        for (int s2 = 0; s2 < nsp; ++s2) {            // ascending sp = ascending pbase
            const unsigned long long* l = base2 + s2 * 16;
            #pragma unroll
            for (int kq = 0; kq < 16; ++kq) {
                unsigned long long e = l[kq];
                float d = __uint_as_float((unsigned int)(e >> 32));
                int pi  = (int)(e & 0xFFFFFFFFu);
                if (d < mval[15]) topk_insert(d, pi, mval, midx);
            }
        }
        float* g = groups + (size_t)mg * K_ * 3;
        #pragma unroll
        for (int kq = 0; kq < 16; ++kq) {
            const float* s = pb + (size_t)midx[kq] * 3;
            g[kq*3+0] = s[0]; g[kq*3+1] = s[1]; g[kq*3+2] = s[2];
        }
    }
}

// ===================== legacy kernels (fallback if no workspace) ============
__global__ __launch_bounds__(FPS_T, 1) void fps_kernel(const float* __restrict__ pos,
                                                       float* __restrict__ cent)
{
    #pragma clang fp contract(off)
    const int b = blockIdx.x;
    const int t = threadIdx.x;
    const float* pb = pos + (size_t)b * NB_ * 3;
    float* cb = cent + (size_t)b * M_ * 3;

    __shared__ float4 spts[NB_];
    __shared__ unsigned long long wkey[2][NWAVE];

    for (int p = t; p < NB_; p += FPS_T) {
        const float* s = pb + (size_t)p * 3;
        spts[p] = make_float4(s[0], s[1], s[2], 0.0f);
    }

    v2f px2[NPAIR], py2[NPAIR], pz2[NPAIR], md2[NPAIR];
    #pragma unroll
    for (int jj = 0; jj < NPAIR; ++jj) {
        const float* s0 = pb + (size_t)(t*PPT + 2*jj) * 3;
        px2[jj] = (v2f){s0[0], s0[3]};
        py2[jj] = (v2f){s0[1], s0[4]};
        pz2[jj] = (v2f){s0[2], s0[5]};
        md2[jj] = (v2f){FLT_MAX, FLT_MAX};
    }
    __syncthreads();

    float lx = pb[0], ly = pb[1], lz = pb[2];
    float c0x=0,c0y=0,c0z=0,c1x=0,c1y=0,c1z=0,c2x=0,c2y=0,c2z=0,c3x=0,c3y=0,c3z=0;

    for (int m = 0; m < M_; ++m) {
        if (t == (m >> 2)) {
            const int sl = m & 3;
            if      (sl == 0) { c0x=lx; c0y=ly; c0z=lz; }
            else if (sl == 1) { c1x=lx; c1y=ly; c1z=lz; }
            else if (sl == 2) { c2x=lx; c2y=ly; c2z=lz; }
            else              { c3x=lx; c3y=ly; c3z=lz; }
        }
        if (m == M_ - 1) break;

        const v2f lxv = {lx,lx}, lyv = {ly,ly}, lzv = {lz,lz};
        v2f bmax2 = {-1.0f, -1.0f};
        #pragma unroll
        for (int jj = 0; jj < NPAIR; ++jj) {
            v2f dx = px2[jj] - lxv;
            v2f dy = py2[jj] - lyv;
            v2f dz = pz2[jj] - lzv;
            v2f d2 = (dx*dx + dy*dy) + dz*dz;
            v2f mj = __builtin_elementwise_min(md2[jj], d2);
            md2[jj] = mj;
            bmax2 = __builtin_elementwise_max(bmax2, mj);
        }
        float bm = fmaxf(bmax2.x, bmax2.y);

        float v = bm;
        {
            int vi;
            vi = __builtin_amdgcn_update_dpp(__float_as_int(v), __float_as_int(v), 0xB1,  0xF, 0xF, false);
            v = fmaxf(v, __int_as_float(vi));
            vi = __builtin_amdgcn_update_dpp(__float_as_int(v), __float_as_int(v), 0x4E,  0xF, 0xF, false);
            v = fmaxf(v, __int_as_float(vi));
            vi = __builtin_amdgcn_update_dpp(__float_as_int(v), __float_as_int(v), 0x141, 0xF, 0xF, false);
            v = fmaxf(v, __int_as_float(vi));
            vi = __builtin_amdgcn_update_dpp(__float_as_int(v), __float_as_int(v), 0x140, 0xF, 0xF, false);
            v = fmaxf(v, __int_as_float(vi));
            vi = __builtin_amdgcn_update_dpp(__float_as_int(v), __float_as_int(v), 0x142, 0xF, 0xF, false);
            v = fmaxf(v, __int_as_float(vi));
            vi = __builtin_amdgcn_update_dpp(__float_as_int(v), __float_as_int(v), 0x143, 0xF, 0xF, false);
            v = fmaxf(v, __int_as_float(vi));
        }
        const float wv = __int_as_float(__builtin_amdgcn_readlane(__float_as_int(v), 63));

        int jp = -1;
        #pragma unroll
        for (int jj = NPAIR - 1; jj >= 0; --jj) {
            if (md2[jj].y == wv) jp = 2*jj + 1;
            if (md2[jj].x == wv) jp = 2*jj;
        }
        const unsigned long long mk = __ballot(jp >= 0);
        const int wl = (int)__ffsll(mk) - 1;
        const int gi = __builtin_amdgcn_readlane(t*PPT + jp, wl);

        const int par = m & 1;
        if ((t & 63) == 0)
            wkey[par][t >> 6] = ((unsigned long long)__float_as_uint(wv) << 32) |
                                (unsigned int)(~gi);
        __syncthreads();

        unsigned long long kk = wkey[par][0];
        #pragma unroll
        for (int w = 1; w < NWAVE; ++w) {
            const unsigned long long e = wkey[par][w];
            kk = (e > kk) ? e : kk;
        }
        const int best = (int)(~(unsigned int)kk);

        const float4 c = spts[best];
        lx = c.x; ly = c.y; lz = c.z;
    }

    {
        float4* o = (float4*)(cb + (size_t)t * 12);
        o[0] = make_float4(c0x, c0y, c0z, c1x);
        o[1] = make_float4(c1y, c1z, c2x, c2y);
        o[2] = make_float4(c2z, c3x, c3y, c3z);
    }
}

__global__ __launch_bounds__(KNN_T, 2) void knn_kernel(const float* __restrict__ pos,
    const float* __restrict__ cent, float* __restrict__ groups,
    unsigned long long* __restrict__ partials, int nsplit)
{
    #pragma clang fp contract(off)
    __shared__ float4 kpts[CHUNK];
    __shared__ unsigned long long sbuf[KNN_T * BSTRIDE];

    const int wg = blockIdx.x;
    const int t  = threadIdx.x;
    const int per_b = 4 * nsplit;
    const int b  = wg / per_b;
    const int r  = wg % per_b;
    const int cg = r / nsplit;
    const int sp = r % nsplit;
    const int span  = NB_ / nsplit;
    const int pbase = sp * span;
    const int nchunks = span / CHUNK;

    const float* pb = pos + (size_t)b * NB_ * 3;
    const int mg = b * M_ + cg * KNN_T + t;
    const float cx = cent[(size_t)mg*3+0];
    const float cy = cent[(size_t)mg*3+1];
    const float cz = cent[(size_t)mg*3+2];
    const float cn2 = (cx*cx + cy*cy) + cz*cz;

    float val[16]; int idx[16];
    #pragma unroll
    for (int j = 0; j < 16; ++j) { val[j] = FLT_MAX; idx[j] = 0; }
    float tau = FLT_MAX;
    int cnt = 0;
    unsigned long long* mybuf = sbuf + t * BSTRIDE;

    for (int c = 0; c < nchunks; ++c) {
        const int ps = pbase + c * CHUNK;
        __syncthreads();
        for (int p = t; p < CHUNK; p += KNN_T) {
            const float* s = pb + (size_t)(ps + p) * 3;
            float x = s[0], y = s[1], z = s[2];
            float pn2 = (x*x + y*y) + z*z;
            kpts[p] = make_float4(x, y, z, pn2);
        }
        __syncthreads();

        for (int p0 = 0; p0 < CHUNK; p0 += GRP) {
            if (__any(cnt > BCAP - GRP)) {
                int n = cnt; cnt = 0;
                for (int i = 0; i < n; ++i) {
                    unsigned long long e = mybuf[i];
                    float d = __uint_as_float((unsigned int)(e >> 32));
                    int pi  = (int)(e & 0xFFFFFFFFu);
                    if (d < val[15]) topk_insert(d, pi, val, idx);
                }
                tau = val[15];
            }
            float4 q[GRP];
            #pragma unroll
            for (int i = 0; i < GRP; ++i) q[i] = kpts[p0 + i];
            float d2v[GRP];
            #pragma unroll
            for (int i = 0; i < GRP; ++i) {
                float dot = __builtin_fmaf(cz, q[i].z,
                            __builtin_fmaf(cy, q[i].y, cx * q[i].x));
                d2v[i] = (cn2 - 2.0f*dot) + q[i].w;
            }
            #pragma unroll
            for (int i = 0; i < GRP; ++i) {
                if (d2v[i] < tau) {
                    mybuf[cnt] = ((unsigned long long)__float_as_uint(d2v[i]) << 32) |
                                 (unsigned int)(ps + p0 + i);
                    ++cnt;
                }
            }
        }
    }
    {
        int n = cnt;
        for (int i = 0; i < n; ++i) {
            unsigned long long e = mybuf[i];
            float d = __uint_as_float((unsigned int)(e >> 32));
            int pi  = (int)(e & 0xFFFFFFFFu);
            if (d < val[15]) topk_insert(d, pi, val, idx);
        }
    }

    if (nsplit > 1) {
        unsigned long long* o = partials + ((size_t)mg * nsplit + sp) * 16;
        #pragma unroll
        for (int kq = 0; kq < 16; ++kq)
            o[kq] = ((unsigned long long)__float_as_uint(val[kq]) << 32) | (unsigned int)idx[kq];
    } else {
        float* g = groups + (size_t)mg * K_ * 3;
        #pragma unroll
        for (int kq = 0; kq < 16; ++kq) {
            const float* s = pb + (size_t)idx[kq] * 3;
            g[kq*3+0] = s[0]; g[kq*3+1] = s[1]; g[kq*3+2] = s[2];
        }
    }
}

__global__ __launch_bounds__(256, 2) void knn_merge(const float* __restrict__ pos,
    const unsigned long long* __restrict__ partials, float* __restrict__ groups,
    int nsplit)
{
    const int mg = blockIdx.x * 256 + threadIdx.x;
    const int b  = mg >> 10;
    const float* pb = pos + (size_t)b * NB_ * 3;

    float val[16]; int idx[16];
    #pragma unroll
    for (int j = 0; j < 16; ++j) { val[j] = FLT_MAX; idx[j] = 0; }
    for (int sp = 0; sp < nsplit; ++sp) {
        const unsigned long long* l = partials + ((size_t)mg * nsplit + sp) * 16;
        #pragma unroll
        for (int kq = 0; kq < 16; ++kq) {
            unsigned long long e = l[kq];
            float d = __uint_as_float((unsigned int)(e >> 32));
            int pi  = (int)(e & 0xFFFFFFFFu);
            if (d < val[15]) topk_insert(d, pi, val, idx);
        }
    }
    float* g = groups + (size_t)mg * K_ * 3;
    #pragma unroll
    for (int kq = 0; kq < 16; ++kq) {
        const float* s = pb + (size_t)idx[kq] * 3;
        g[kq*3+0] = s[0]; g[kq*3+1] = s[1]; g[kq*3+2] = s[2];
    }
}

// ============================= host =============================
extern "C" void kernel_launch(void* const* d_in, const int* in_sizes, int n_in,
                              void* d_out, int out_size, void* d_ws, size_t ws_size,
                              hipStream_t stream)
{
    (void)in_sizes; (void)n_in; (void)out_size;
    const float* pos = (const float*)d_in[1];   // d_in[0]=x (unused), d_in[2]=batch (unused)
    float* out    = (float*)d_out;
    float* cent   = out;                         // (B*M, 3)
    float* groups = out + (size_t)B_ * M_ * 3;   // (B*M*K, 3)

    const size_t FLAGS = 256;   // progress[16] u32 + merge counters[48] u32 = 256 B
    // partials: chunks 1-3, 768 centroids/batch, 8 slots, 16 entries x 8B = 12.6 MB
    const size_t PART  = (size_t)B_ * 768 * MAXSP * 16 * sizeof(unsigned long long);

    if (ws_size >= FLAGS + PART) {
        unsigned int* progress = (unsigned int*)d_ws;
        unsigned long long* partials = (unsigned long long*)((char*)d_ws + FLAGS);

        hipMemsetAsync(d_ws, 0, FLAGS, stream);   // re-poison-safe flags + tickets

        fused_kernel<<<FPS_BLOCKS + KNN_BLOCKS, FPS_T, 0, stream>>>(pos, cent, groups,
                                                                    partials, progress);
    } else {
        // legacy sequential path (verified round-0 behavior)
        fps_kernel<<<B_, FPS_T, 0, stream>>>(pos, cent);
        const size_t lst = (size_t)B_ * M_ * 16 * sizeof(unsigned long long);
        int nsplit = (ws_size >= 8*lst) ? 8 : (ws_size >= 4*lst) ? 4 :
                     (ws_size >= 2*lst) ? 2 : 1;
        knn_kernel<<<B_ * 4 * nsplit, KNN_T, 0, stream>>>(pos, cent, groups,
                                                          (unsigned long long*)d_ws, nsplit);
        if (nsplit > 1)
            knn_merge<<<(B_ * M_) / 256, 256, 0, stream>>>(pos,
                (const unsigned long long*)d_ws, groups, nsplit);
    }
}

// Round 8
// 1250.364 us; speedup vs baseline: 1.1647x; 1.1647x over previous
//
#include <hip/hip_runtime.h>
#include <float.h>
#include <math.h>

#define B_   16
#define NB_  8192
#define M_   1024
#define K_   16

// ===================== FROZEN ARITHMETIC (verified absmax==0, rounds 5-8) ==
// FPS d2:  dx=px-lx... d2=(dx*dx+dy*dy)+dz*dz   f32, no FMA (contract off)
//          (packed v_pk_* f32 ops are per-half IEEE-identical to scalar)
// kNN:     pn2/cn2 ascending no-FMA; dot=fma(cz,qz,fma(cy,qy,cx*qx));
//          d2=(cn2-2f*dot)+pn2
// Ties: strictly-first occurrence (lowest index) everywhere.
// R16: REVERT R15's coord piggyback (per-lane spts[t*PPT+js] read = 512B lane
// stride = all 64 lanes on bank 0 -> 3.83M conflicts, +100us on the serial
// chain). Clean composition of ONLY verified parts, zero new variables:
//   FPS   = R10-verbatim (937us measured; plain v2f, spts[best] broadcast)
//   kNN   = R10-verbatim scan (fused=1166 measured with this scan)
//   merge = in-kernel ticket w/ t0-fence (absmax=0 across R13-R15; adds ~0 to
//           tail per R14 decomposition; kills the 101us separate-merge epilogue)
// Pre-committed: if total >= ~1205 (wash vs 1208.7 baseline), the ceiling is
// structural (1023 serial argmax steps + ~230us scan floor) -> declare ledger.
// ===========================================================================

typedef float v2f __attribute__((ext_vector_type(2)));

#define FPS_T 256
#define PPT   32
#define NPAIR (PPT/2)
#define NWAVE (FPS_T/64)

#define KNN_T   256
#define CHUNK   1024
#define GRP     8
#define BCAP    16
#define BSTRIDE 17

#define FPS_BLOCKS B_
#define WGS_PER_B  15            // chunk splits 1+2+4+8
#define KNN_BLOCKS (B_ * WGS_PER_B)   // 240
#define MAXSP      8             // partial slots per centroid (chunks 1-3)

// stable sorted insert into ascending top-16 (ties keep earlier/lower index)
__device__ __forceinline__ void topk_insert(float d2, int pi, float val[16], int idx[16])
{
    int r = 0;
    #pragma unroll
    for (int j = 0; j < 16; ++j) r += (val[j] <= d2) ? 1 : 0;
    #pragma unroll
    for (int j = 15; j >= 1; --j) {
        bool sh = (j > r);
        val[j] = sh ? val[j-1] : val[j];
        idx[j] = sh ? idx[j-1] : idx[j];
    }
    #pragma unroll
    for (int j = 0; j < 16; ++j) {
        bool pl = (j == r);
        val[j] = pl ? d2 : val[j];
        idx[j] = pl ? pi : idx[j];
    }
}

// ============================= fused FPS + kNN =============================
__global__ __launch_bounds__(FPS_T, 1) void fused_kernel(
    const float* __restrict__ pos, float* __restrict__ cent,
    float* __restrict__ groups, unsigned long long* __restrict__ partials,
    unsigned int* __restrict__ progress)
{
    #pragma clang fp contract(off)
    __shared__ float4 spts[NB_];                        // FPS: 128 KB table; kNN carves prefix
    __shared__ unsigned long long wkey[2][NWAVE];       // FPS keys; kNN ticket scratch

    const int blk = blockIdx.x;
    const int t   = threadIdx.x;

    if (blk < FPS_BLOCKS) {
        // ================= FPS role (R10-verbatim, 937us measured) ================
        const int b = blk;
        const float* pb = pos + (size_t)b * NB_ * 3;
        float* cb = cent + (size_t)b * M_ * 3;

        for (int p = t; p < NB_; p += FPS_T) {
            const float* s = pb + (size_t)p * 3;
            spts[p] = make_float4(s[0], s[1], s[2], 0.0f);
        }

        v2f px2[NPAIR], py2[NPAIR], pz2[NPAIR], md2[NPAIR];
        #pragma unroll
        for (int jj = 0; jj < NPAIR; ++jj) {
            const float* s0 = pb + (size_t)(t*PPT + 2*jj) * 3;
            px2[jj] = (v2f){s0[0], s0[3]};
            py2[jj] = (v2f){s0[1], s0[4]};
            pz2[jj] = (v2f){s0[2], s0[5]};
            md2[jj] = (v2f){FLT_MAX, FLT_MAX};
        }
        __syncthreads();

        float lx = pb[0], ly = pb[1], lz = pb[2];   // deterministic start at idx 0
        // thread t owns centroids 4t..4t+3 (named regs: no dynamic indexing)
        float c0x=0,c0y=0,c0z=0,c1x=0,c1y=0,c1z=0,c2x=0,c2y=0,c2z=0,c3x=0,c3y=0,c3z=0;

        for (int m = 0; m < M_; ++m) {
            if (t == (m >> 2)) {
                const int sl = m & 3;
                if      (sl == 0) { c0x=lx; c0y=ly; c0z=lz; }
                else if (sl == 1) { c1x=lx; c1y=ly; c1z=lz; }
                else if (sl == 2) { c2x=lx; c2y=ly; c2z=lz; }
                else              { c3x=lx; c3y=ly; c3z=lz; }
            }

            // ---- chunk flush: wave cg publishes centroids [256cg, 256cg+255] ----
            if ((m & 255) == 255) {
                const int cg = m >> 8;
                if ((t >> 6) == cg) {                       // thread t owns 4t..4t+3
                    float4* o = (float4*)(cb + (size_t)t * 12);
                    o[0] = make_float4(c0x, c0y, c0z, c1x);
                    o[1] = make_float4(c1y, c1z, c2x, c2y);
                    o[2] = make_float4(c2z, c3x, c3y, c3z);
                    if ((t & 63) == 0)                      // lane0 of wave cg: release
                        __hip_atomic_store(&progress[b], (unsigned)(cg + 1),
                                           __ATOMIC_RELEASE, __HIP_MEMORY_SCOPE_AGENT);
                }
            }
            if (m == M_ - 1) break;

            // ---- packed update + packed running max (frozen, r8-verified) ----
            const v2f lxv = {lx,lx}, lyv = {ly,ly}, lzv = {lz,lz};
            v2f bmax2 = {-1.0f, -1.0f};
            #pragma unroll
            for (int jj = 0; jj < NPAIR; ++jj) {
                v2f dx = px2[jj] - lxv;
                v2f dy = py2[jj] - lyv;
                v2f dz = pz2[jj] - lzv;
                v2f d2 = (dx*dx + dy*dy) + dz*dz;       // pk mul/add, frozen rounding
                v2f mj = __builtin_elementwise_min(md2[jj], d2);
                md2[jj] = mj;
                bmax2 = __builtin_elementwise_max(bmax2, mj);
            }
            float bm = fmaxf(bmax2.x, bmax2.y);

            // ---- wave f32 max via DPP (r7/r8-verified chain) ----
            float v = bm;
            {
                int vi;
                vi = __builtin_amdgcn_update_dpp(__float_as_int(v), __float_as_int(v), 0xB1,  0xF, 0xF, false);
                v = fmaxf(v, __int_as_float(vi));
                vi = __builtin_amdgcn_update_dpp(__float_as_int(v), __float_as_int(v), 0x4E,  0xF, 0xF, false);
                v = fmaxf(v, __int_as_float(vi));
                vi = __builtin_amdgcn_update_dpp(__float_as_int(v), __float_as_int(v), 0x141, 0xF, 0xF, false);
                v = fmaxf(v, __int_as_float(vi));
                vi = __builtin_amdgcn_update_dpp(__float_as_int(v), __float_as_int(v), 0x140, 0xF, 0xF, false);
                v = fmaxf(v, __int_as_float(vi));
                vi = __builtin_amdgcn_update_dpp(__float_as_int(v), __float_as_int(v), 0x142, 0xF, 0xF, false);
                v = fmaxf(v, __int_as_float(vi));
                vi = __builtin_amdgcn_update_dpp(__float_as_int(v), __float_as_int(v), 0x143, 0xF, 0xF, false);
                v = fmaxf(v, __int_as_float(vi));
            }
            const float wv = __int_as_float(__builtin_amdgcn_readlane(__float_as_int(v), 63));

            // ---- per-lane first-match scan (descending overwrite => lowest idx) ----
            int jp = -1;
            #pragma unroll
            for (int jj = NPAIR - 1; jj >= 0; --jj) {
                if (md2[jj].y == wv) jp = 2*jj + 1;
                if (md2[jj].x == wv) jp = 2*jj;
            }
            const unsigned long long mk = __ballot(jp >= 0);
            const int wl = (int)__ffsll(mk) - 1;            // lowest lane == lowest block
            const int gi = __builtin_amdgcn_readlane(t*PPT + jp, wl);

            const int par = m & 1;
            if ((t & 63) == 0)
                wkey[par][t >> 6] = ((unsigned long long)__float_as_uint(wv) << 32) |
                                    (unsigned int)(~gi);    // bigger ~idx == lower idx
            __syncthreads();                                // the ONLY barrier

            unsigned long long kk = wkey[par][0];
            #pragma unroll
            for (int w = 1; w < NWAVE; ++w) {
                const unsigned long long e = wkey[par][w];
                kk = (e > kk) ? e : kk;
            }
            const int best = (int)(~(unsigned int)kk);

            const float4 c = spts[best];                    // b128 LDS broadcast
            lx = c.x; ly = c.y; lz = c.z;
        }
        return;
    }

    // ================= kNN role (R10-verified loop, verbatim) =================
    // per batch: 15 WGs -> chunk0 split1, chunk1 split2, chunk2 split4, chunk3 split8
    const int r = blk - FPS_BLOCKS;          // 0..239
    const int b = r / WGS_PER_B;
    const int w = r % WGS_PER_B;
    int cg, sp;
    if      (w == 0) { cg = 0; sp = 0; }
    else if (w < 3)  { cg = 1; sp = w - 1; }
    else if (w < 7)  { cg = 2; sp = w - 3; }
    else             { cg = 3; sp = w - 7; }
    const int span   = NB_ >> cg;
    const int pbase  = sp * span;
    const int direct = (cg == 0);
    const int nchunks = span / CHUNK;

    // carve kNN LDS out of the (unused-by-this-role) 128KB table
    float4* kpts = spts;                                              // 16 KB: x,y,z,pn2
    unsigned long long* sbuf = (unsigned long long*)(spts + CHUNK);   // ~34 KB

    const float* pb = pos + (size_t)b * NB_ * 3;

    // ---- pre-stage first chunk BEFORE the wait (centroid-independent) ----
    for (int p = t; p < CHUNK; p += KNN_T) {
        const float* s = pb + (size_t)(pbase + p) * 3;
        float x = s[0], y = s[1], z = s[2];
        float pn2 = (x*x + y*y) + z*z;               // ascending, no fma
        kpts[p] = make_float4(x, y, z, pn2);
    }

    // wait for producer: chunk cg's centroids are final once progress[b] > cg
    if (t == 0) {
        while (__hip_atomic_load(&progress[b], __ATOMIC_ACQUIRE,
                                 __HIP_MEMORY_SCOPE_AGENT) < (unsigned)(cg + 1))
            __builtin_amdgcn_s_sleep(64);
    }
    __syncthreads();                                  // wake + staging barrier

    const int mg = b * M_ + cg * KNN_T + t;
    const float cx = cent[(size_t)mg*3+0];
    const float cy = cent[(size_t)mg*3+1];
    const float cz = cent[(size_t)mg*3+2];
    const float cn2 = (cx*cx + cy*cy) + cz*cz;        // ascending, no fma

    float val[16]; int idx[16];
    #pragma unroll
    for (int j = 0; j < 16; ++j) { val[j] = FLT_MAX; idx[j] = 0; }
    float tau = FLT_MAX;
    int cnt = 0;
    unsigned long long* mybuf = sbuf + t * BSTRIDE;

    for (int c = 0; c < nchunks; ++c) {
        const int ps = pbase + c * CHUNK;

        for (int p0 = 0; p0 < CHUNK; p0 += GRP) {
            // make room BEFORE the group (appends per group <= GRP=8)
            if (__any(cnt > BCAP - GRP)) {
                int n = cnt; cnt = 0;
                for (int i = 0; i < n; ++i) {
                    unsigned long long e = mybuf[i];
                    float d = __uint_as_float((unsigned int)(e >> 32));
                    int pi  = (int)(e & 0xFFFFFFFFu);
                    if (d < val[15]) topk_insert(d, pi, val, idx);
                }
                tau = val[15];
            }
            float4 q[GRP];
            #pragma unroll
            for (int i = 0; i < GRP; ++i) q[i] = kpts[p0 + i];   // batched b128 reads
            float d2v[GRP];
            #pragma unroll
            for (int i = 0; i < GRP; ++i) {
                float dot = __builtin_fmaf(cz, q[i].z,
                            __builtin_fmaf(cy, q[i].y, cx * q[i].x)); // Eigen gemm k-rem
                d2v[i] = (cn2 - 2.0f*dot) + q[i].w;                   // no fma
            }
            #pragma unroll
            for (int i = 0; i < GRP; ++i) {
                if (d2v[i] < tau) {
                    mybuf[cnt] = ((unsigned long long)__float_as_uint(d2v[i]) << 32) |
                                 (unsigned int)(ps + p0 + i);
                    ++cnt;
                }
            }
        }

        if (c + 1 < nchunks) {                        // stage next chunk
            __syncthreads();
            const int ns = pbase + (c + 1) * CHUNK;
            for (int p = t; p < CHUNK; p += KNN_T) {
                const float* s = pb + (size_t)(ns + p) * 3;
                float x = s[0], y = s[1], z = s[2];
                float pn2 = (x*x + y*y) + z*z;        // ascending, no fma
                kpts[p] = make_float4(x, y, z, pn2);
            }
            __syncthreads();
        }
    }
    { // final flush
        int n = cnt;
        for (int i = 0; i < n; ++i) {
            unsigned long long e = mybuf[i];
            float d = __uint_as_float((unsigned int)(e >> 32));
            int pi  = (int)(e & 0xFFFFFFFFu);
            if (d < val[15]) topk_insert(d, pi, val, idx);
        }
    }

    if (direct) {
        float* g = groups + (size_t)mg * K_ * 3;
        #pragma unroll
        for (int kq = 0; kq < 16; ++kq) {
            const float* s = pb + (size_t)idx[kq] * 3;
            g[kq*3+0] = s[0]; g[kq*3+1] = s[1]; g[kq*3+2] = s[2];
        }
        return;
    }

    // ---- partial write + ticket: last split WG merges in-kernel (R13-R15 verified)
    const int cidx = b * 3 + (cg - 1);
    const int nsp  = 1 << cg;                         // 2 / 4 / 8
    {
        unsigned long long* o = partials + (((size_t)cidx * 256 + t) * MAXSP + sp) * 16;
        #pragma unroll
        for (int kq = 0; kq < 16; ++kq)
            o[kq] = ((unsigned long long)__float_as_uint(val[kq]) << 32) | (unsigned int)idx[kq];
    }
    __syncthreads();                                  // all waves' stores drained (vmcnt)
    unsigned int* counters = progress + 16;           // 48 u32, zeroed by host memset
    if (t == 0) {
        __threadfence();                              // writeback this XCD's L2 (release)
        wkey[0][0] = (unsigned long long)atomicAdd(&counters[cidx], 1u);
    }
    __syncthreads();
    if ((unsigned)wkey[0][0] != (unsigned)(nsp - 1))
        return;                                       // not last: done

    __threadfence();                                  // acquire other splits' partials
    {
        float mval[16]; int midx[16];
        #pragma unroll
        for (int j = 0; j < 16; ++j) { mval[j] = FLT_MAX; midx[j] = 0; }
        const unsigned long long* base2 = partials + (((size_t)cidx * 256 + t) * MAXSP) * 16;
        for (int s2 = 0; s2 < nsp; ++s2) {            // ascending sp = ascending pbase
            const unsigned long long* l = base2 + s2 * 16;
            #pragma unroll
            for (int kq = 0; kq < 16; ++kq) {
                unsigned long long e = l[kq];
                float d = __uint_as_float((unsigned int)(e >> 32));
                int pi  = (int)(e & 0xFFFFFFFFu);
                if (d < mval[15]) topk_insert(d, pi, mval, midx);
            }
        }
        float* g = groups + (size_t)mg * K_ * 3;
        #pragma unroll
        for (int kq = 0; kq < 16; ++kq) {
            const float* s = pb + (size_t)midx[kq] * 3;
            g[kq*3+0] = s[0]; g[kq*3+1] = s[1]; g[kq*3+2] = s[2];
        }
    }
}

// ===================== legacy kernels (fallback if no workspace) ============
__global__ __launch_bounds__(FPS_T, 1) void fps_kernel(const float* __restrict__ pos,
                                                       float* __restrict__ cent)
{
    #pragma clang fp contract(off)
    const int b = blockIdx.x;
    const int t = threadIdx.x;
    const float* pb = pos + (size_t)b * NB_ * 3;
    float* cb = cent + (size_t)b * M_ * 3;

    __shared__ float4 spts[NB_];
    __shared__ unsigned long long wkey[2][NWAVE];

    for (int p = t; p < NB_; p += FPS_T) {
        const float* s = pb + (size_t)p * 3;
        spts[p] = make_float4(s[0], s[1], s[2], 0.0f);
    }

    v2f px2[NPAIR], py2[NPAIR], pz2[NPAIR], md2[NPAIR];
    #pragma unroll
    for (int jj = 0; jj < NPAIR; ++jj) {
        const float* s0 = pb + (size_t)(t*PPT + 2*jj) * 3;
        px2[jj] = (v2f){s0[0], s0[3]};
        py2[jj] = (v2f){s0[1], s0[4]};
        pz2[jj] = (v2f){s0[2], s0[5]};
        md2[jj] = (v2f){FLT_MAX, FLT_MAX};
    }
    __syncthreads();

    float lx = pb[0], ly = pb[1], lz = pb[2];
    float c0x=0,c0y=0,c0z=0,c1x=0,c1y=0,c1z=0,c2x=0,c2y=0,c2z=0,c3x=0,c3y=0,c3z=0;

    for (int m = 0; m < M_; ++m) {
        if (t == (m >> 2)) {
            const int sl = m & 3;
            if      (sl == 0) { c0x=lx; c0y=ly; c0z=lz; }
            else if (sl == 1) { c1x=lx; c1y=ly; c1z=lz; }
            else if (sl == 2) { c2x=lx; c2y=ly; c2z=lz; }
            else              { c3x=lx; c3y=ly; c3z=lz; }
        }
        if (m == M_ - 1) break;

        const v2f lxv = {lx,lx}, lyv = {ly,ly}, lzv = {lz,lz};
        v2f bmax2 = {-1.0f, -1.0f};
        #pragma unroll
        for (int jj = 0; jj < NPAIR; ++jj) {
            v2f dx = px2[jj] - lxv;
            v2f dy = py2[jj] - lyv;
            v2f dz = pz2[jj] - lzv;
            v2f d2 = (dx*dx + dy*dy) + dz*dz;
            v2f mj = __builtin_elementwise_min(md2[jj], d2);
            md2[jj] = mj;
            bmax2 = __builtin_elementwise_max(bmax2, mj);
        }
        float bm = fmaxf(bmax2.x, bmax2.y);

        float v = bm;
        {
            int vi;
            vi = __builtin_amdgcn_update_dpp(__float_as_int(v), __float_as_int(v), 0xB1,  0xF, 0xF, false);
            v = fmaxf(v, __int_as_float(vi));
            vi = __builtin_amdgcn_update_dpp(__float_as_int(v), __float_as_int(v), 0x4E,  0xF, 0xF, false);
            v = fmaxf(v, __int_as_float(vi));
            vi = __builtin_amdgcn_update_dpp(__float_as_int(v), __float_as_int(v), 0x141, 0xF, 0xF, false);
            v = fmaxf(v, __int_as_float(vi));
            vi = __builtin_amdgcn_update_dpp(__float_as_int(v), __float_as_int(v), 0x140, 0xF, 0xF, false);
            v = fmaxf(v, __int_as_float(vi));
            vi = __builtin_amdgcn_update_dpp(__float_as_int(v), __float_as_int(v), 0x142, 0xF, 0xF, false);
            v = fmaxf(v, __int_as_float(vi));
            vi = __builtin_amdgcn_update_dpp(__float_as_int(v), __float_as_int(v), 0x143, 0xF, 0xF, false);
            v = fmaxf(v, __int_as_float(vi));
        }
        const float wv = __int_as_float(__builtin_amdgcn_readlane(__float_as_int(v), 63));

        int jp = -1;
        #pragma unroll
        for (int jj = NPAIR - 1; jj >= 0; --jj) {
            if (md2[jj].y == wv) jp = 2*jj + 1;
            if (md2[jj].x == wv) jp = 2*jj;
        }
        const unsigned long long mk = __ballot(jp >= 0);
        const int wl = (int)__ffsll(mk) - 1;
        const int gi = __builtin_amdgcn_readlane(t*PPT + jp, wl);

        const int par = m & 1;
        if ((t & 63) == 0)
            wkey[par][t >> 6] = ((unsigned long long)__float_as_uint(wv) << 32) |
                                (unsigned int)(~gi);
        __syncthreads();

        unsigned long long kk = wkey[par][0];
        #pragma unroll
        for (int w = 1; w < NWAVE; ++w) {
            const unsigned long long e = wkey[par][w];
            kk = (e > kk) ? e : kk;
        }
        const int best = (int)(~(unsigned int)kk);

        const float4 c = spts[best];
        lx = c.x; ly = c.y; lz = c.z;
    }

    {
        float4* o = (float4*)(cb + (size_t)t * 12);
        o[0] = make_float4(c0x, c0y, c0z, c1x);
        o[1] = make_float4(c1y, c1z, c2x, c2y);
        o[2] = make_float4(c2z, c3x, c3y, c3z);
    }
}

__global__ __launch_bounds__(KNN_T, 2) void knn_kernel(const float* __restrict__ pos,
    const float* __restrict__ cent, float* __restrict__ groups,
    unsigned long long* __restrict__ partials, int nsplit)
{
    #pragma clang fp contract(off)
    __shared__ float4 kpts[CHUNK];
    __shared__ unsigned long long sbuf[KNN_T * BSTRIDE];

    const int wg = blockIdx.x;
    const int t  = threadIdx.x;
    const int per_b = 4 * nsplit;
    const int b  = wg / per_b;
    const int r  = wg % per_b;
    const int cg = r / nsplit;
    const int sp = r % nsplit;
    const int span  = NB_ / nsplit;
    const int pbase = sp * span;
    const int nchunks = span / CHUNK;

    const float* pb = pos + (size_t)b * NB_ * 3;
    const int mg = b * M_ + cg * KNN_T + t;
    const float cx = cent[(size_t)mg*3+0];
    const float cy = cent[(size_t)mg*3+1];
    const float cz = cent[(size_t)mg*3+2];
    const float cn2 = (cx*cx + cy*cy) + cz*cz;

    float val[16]; int idx[16];
    #pragma unroll
    for (int j = 0; j < 16; ++j) { val[j] = FLT_MAX; idx[j] = 0; }
    float tau = FLT_MAX;
    int cnt = 0;
    unsigned long long* mybuf = sbuf + t * BSTRIDE;

    for (int c = 0; c < nchunks; ++c) {
        const int ps = pbase + c * CHUNK;
        __syncthreads();
        for (int p = t; p < CHUNK; p += KNN_T) {
            const float* s = pb + (size_t)(ps + p) * 3;
            float x = s[0], y = s[1], z = s[2];
            float pn2 = (x*x + y*y) + z*z;
            kpts[p] = make_float4(x, y, z, pn2);
        }
        __syncthreads();

        for (int p0 = 0; p0 < CHUNK; p0 += GRP) {
            if (__any(cnt > BCAP - GRP)) {
                int n = cnt; cnt = 0;
                for (int i = 0; i < n; ++i) {
                    unsigned long long e = mybuf[i];
                    float d = __uint_as_float((unsigned int)(e >> 32));
                    int pi  = (int)(e & 0xFFFFFFFFu);
                    if (d < val[15]) topk_insert(d, pi, val, idx);
                }
                tau = val[15];
            }
            float4 q[GRP];
            #pragma unroll
            for (int i = 0; i < GRP; ++i) q[i] = kpts[p0 + i];
            float d2v[GRP];
            #pragma unroll
            for (int i = 0; i < GRP; ++i) {
                float dot = __builtin_fmaf(cz, q[i].z,
                            __builtin_fmaf(cy, q[i].y, cx * q[i].x));
                d2v[i] = (cn2 - 2.0f*dot) + q[i].w;
            }
            #pragma unroll
            for (int i = 0; i < GRP; ++i) {
                if (d2v[i] < tau) {
                    mybuf[cnt] = ((unsigned long long)__float_as_uint(d2v[i]) << 32) |
                                 (unsigned int)(ps + p0 + i);
                    ++cnt;
                }
            }
        }
    }
    {
        int n = cnt;
        for (int i = 0; i < n; ++i) {
            unsigned long long e = mybuf[i];
            float d = __uint_as_float((unsigned int)(e >> 32));
            int pi  = (int)(e & 0xFFFFFFFFu);
            if (d < val[15]) topk_insert(d, pi, val, idx);
        }
    }

    if (nsplit > 1) {
        unsigned long long* o = partials + ((size_t)mg * nsplit + sp) * 16;
        #pragma unroll
        for (int kq = 0; kq < 16; ++kq)
            o[kq] = ((unsigned long long)__float_as_uint(val[kq]) << 32) | (unsigned int)idx[kq];
    } else {
        float* g = groups + (size_t)mg * K_ * 3;
        #pragma unroll
        for (int kq = 0; kq < 16; ++kq) {
            const float* s = pb + (size_t)idx[kq] * 3;
            g[kq*3+0] = s[0]; g[kq*3+1] = s[1]; g[kq*3+2] = s[2];
        }
    }
}

__global__ __launch_bounds__(256, 2) void knn_merge(const float* __restrict__ pos,
    const unsigned long long* __restrict__ partials, float* __restrict__ groups,
    int nsplit)
{
    const int mg = blockIdx.x * 256 + threadIdx.x;
    const int b  = mg >> 10;
    const float* pb = pos + (size_t)b * NB_ * 3;

    float val[16]; int idx[16];
    #pragma unroll
    for (int j = 0; j < 16; ++j) { val[j] = FLT_MAX; idx[j] = 0; }
    for (int sp = 0; sp < nsplit; ++sp) {
        const unsigned long long* l = partials + ((size_t)mg * nsplit + sp) * 16;
        #pragma unroll
        for (int kq = 0; kq < 16; ++kq) {
            unsigned long long e = l[kq];
            float d = __uint_as_float((unsigned int)(e >> 32));
            int pi  = (int)(e & 0xFFFFFFFFu);
            if (d < val[15]) topk_insert(d, pi, val, idx);
        }
    }
    float* g = groups + (size_t)mg * K_ * 3;
    #pragma unroll
    for (int kq = 0; kq < 16; ++kq) {
        const float* s = pb + (size_t)idx[kq] * 3;
        g[kq*3+0] = s[0]; g[kq*3+1] = s[1]; g[kq*3+2] = s[2];
    }
}

// ============================= host =============================
extern "C" void kernel_launch(void* const* d_in, const int* in_sizes, int n_in,
                              void* d_out, int out_size, void* d_ws, size_t ws_size,
                              hipStream_t stream)
{
    (void)in_sizes; (void)n_in; (void)out_size;
    const float* pos = (const float*)d_in[1];   // d_in[0]=x (unused), d_in[2]=batch (unused)
    float* out    = (float*)d_out;
    float* cent   = out;                         // (B*M, 3)
    float* groups = out + (size_t)B_ * M_ * 3;   // (B*M*K, 3)

    const size_t FLAGS = 256;   // progress[16] u32 + merge counters[48] u32 = 256 B
    // partials: chunks 1-3, 768 centroids/batch, 8 slots, 16 entries x 8B = 12.6 MB
    const size_t PART  = (size_t)B_ * 768 * MAXSP * 16 * sizeof(unsigned long long);

    if (ws_size >= FLAGS + PART) {
        unsigned int* progress = (unsigned int*)d_ws;
        unsigned long long* partials = (unsigned long long*)((char*)d_ws + FLAGS);

        hipMemsetAsync(d_ws, 0, FLAGS, stream);   // re-poison-safe flags + tickets

        fused_kernel<<<FPS_BLOCKS + KNN_BLOCKS, FPS_T, 0, stream>>>(pos, cent, groups,
                                                                    partials, progress);
    } else {
        // legacy sequential path (verified round-0 behavior)
        fps_kernel<<<B_, FPS_T, 0, stream>>>(pos, cent);
        const size_t lst = (size_t)B_ * M_ * 16 * sizeof(unsigned long long);
        int nsplit = (ws_size >= 8*lst) ? 8 : (ws_size >= 4*lst) ? 4 :
                     (ws_size >= 2*lst) ? 2 : 1;
        knn_kernel<<<B_ * 4 * nsplit, KNN_T, 0, stream>>>(pos, cent, groups,
                                                          (unsigned long long*)d_ws, nsplit);
        if (nsplit > 1)
            knn_merge<<<(B_ * M_) / 256, 256, 0, stream>>>(pos,
                (const unsigned long long*)d_ws, groups, nsplit);
    }
}